// Round 15
// baseline (682.273 us; speedup 1.0000x reference)
//
#include <hip/hip_runtime.h>
#include <cfloat>

#define NRW 32768
#define KC 4096
#define CD 256
#define HW 1024
#define CAP 64
#define WIN 1e-3f

typedef short bf16x8 __attribute__((ext_vector_type(8)));
typedef float f32x4 __attribute__((ext_vector_type(4)));

__device__ __forceinline__ unsigned short f2bf(float f) {  // RNE f32->bf16
  unsigned int u = __float_as_uint(f);
  u = (u + 0x7FFFu + ((u >> 16) & 1u)) >> 16;
  return (unsigned short)u;
}

// ---------- se[k] = np.sum(cb[k]**2) : numpy pairwise (128+128, scalar 8-acc) [verified] ----------
__global__ __launch_bounds__(256) void vq_se(const float* __restrict__ cb,
                                             float* __restrict__ se) {
#pragma clang fp contract(off)
  const int tid = threadIdx.x;
  const int g = tid >> 3;
  const int j = tid & 7;
  const int code = blockIdx.x * 32 + g;
  const float* e = cb + (size_t)code * CD;
  float half[2];
#pragma unroll
  for (int h = 0; h < 2; ++h) {
    const float* a = e + h * 128;
    float v = a[j];
    float r = v * v;
#pragma unroll
    for (int i = 1; i < 16; ++i) {
      float w = a[8 * i + j];
      float w2 = w * w;
      r = r + w2;
    }
    float l1 = r + __shfl_down(r, 1, 8);
    float l2 = l1 + __shfl_down(l1, 2, 8);
    float l3 = l2 + __shfl_down(l2, 4, 8);
    half[h] = l3;
  }
  if (j == 0) se[code] = half[0] + half[1];
}

// ---------- convert x (B,C,H,W) f32 -> xh[row][ch] bf16 (transpose, RNE) [verified] ----------
__global__ __launch_bounds__(256) void vq_cvt_x(const float* __restrict__ x,
                                                unsigned short* __restrict__ xh) {
  const int t = threadIdx.x;                  // channel
  const int b = blockIdx.x >> 4;
  const int hw0 = (blockIdx.x & 15) << 6;
  const float* src = x + ((size_t)b * CD + t) * HW + hw0;
  unsigned short* dst = xh + ((size_t)b * HW + hw0) * CD + t;
#pragma unroll
  for (int f = 0; f < 16; ++f) {
    const float4 v = *(const float4*)(src + 4 * f);
    dst[(size_t)(4 * f + 0) * CD] = f2bf(v.x);
    dst[(size_t)(4 * f + 1) * CD] = f2bf(v.y);
    dst[(size_t)(4 * f + 2) * CD] = f2bf(v.z);
    dst[(size_t)(4 * f + 3) * CD] = f2bf(v.w);
  }
}

// ---------- convert cb f32 -> eh bf16 (flat) [verified] ----------
__global__ __launch_bounds__(256) void vq_cvt_e(const float* __restrict__ cb,
                                                unsigned short* __restrict__ eh) {
  const int i4 = (blockIdx.x * 256 + threadIdx.x) * 4;
  const float4 v = *(const float4*)(cb + i4);
  ushort4 o;
  o.x = f2bf(v.x); o.y = f2bf(v.y); o.z = f2bf(v.z); o.w = f2bf(v.w);
  *(ushort4*)(eh + i4) = o;
}

// ---------- zero cnt + nflg ----------
__global__ __launch_bounds__(256) void vq_init(int* __restrict__ cnt,
                                               int* __restrict__ nflg) {
  const int i = blockIdx.x * 256 + threadIdx.x;
  cnt[i] = 0;
  if (i == 0) *nflg = 0;
}

// ---------- single-pass MFMA filter GEMM with streaming candidate collection ----------
// 64 rows/block; wave w: rows (w&1)*32..+32, code half (w>>1)*32 of each 64-code group.
// es layout: granule (c8, code) -> es[buf][(c8*64+code)*8 .. +8]  (conflict-free b128 reads)
__global__ __launch_bounds__(256) void vq_gemm(const unsigned short* __restrict__ xh,
                                               const unsigned short* __restrict__ eh,
                                               const float* __restrict__ se,
                                               int* __restrict__ cnt,
                                               int* __restrict__ cand) {
  __shared__ unsigned short es[2][64 * 256];  // 2 x 32 KB double buffer

  const int t = threadIdx.x;
  const int l = t & 63;
  const int w = t >> 6;
  const int rs = (w & 1) * 32;                // row-slab base within block
  const int ch32 = (w >> 1) * 32;             // code half within cg
  const int rowbase = blockIdx.x * 64;
  const int lq = l >> 4;                      // lane quad 0..3
  const int ll = l & 15;

  // A fragments: 2 slabs x 8 kb, direct from global (resident)
  bf16x8 afr[2][8];
#pragma unroll
  for (int mt = 0; mt < 2; ++mt) {
    const unsigned short* ga = xh + (size_t)(rowbase + rs + 16 * mt + ll) * CD + (lq << 3);
#pragma unroll
    for (int kb = 0; kb < 8; ++kb)
      afr[mt][kb] = *(const bf16x8*)(ga + (kb << 5));
  }

  float run[2][4];
#pragma unroll
  for (int mt = 0; mt < 2; ++mt)
#pragma unroll
    for (int r = 0; r < 4; ++r) run[mt][r] = FLT_MAX;

  // staging regs: thread t -> code co = t>>2, ch segment seg = t&3 (64 shorts)
  const int co = t >> 2, seg = t & 3;
  uint4 stg[8];
  {
    const unsigned short* g = eh + (size_t)co * CD + seg * 64;
#pragma unroll
    for (int u = 0; u < 8; ++u) stg[u] = *(const uint4*)(g + u * 8);
  }

#pragma unroll 1
  for (int cg = 0; cg < 64; ++cg) {
    // publish chunk cg into es[cg&1] (contiguous granule writes)
    {
      unsigned short* dbase = &es[cg & 1][0];
#pragma unroll
      for (int u = 0; u < 8; ++u)
        *(uint4*)&dbase[((seg * 8 + u) * 64 + co) * 8] = stg[u];
    }
    // prefetch chunk cg+1 into regs (latency hides under MFMAs below)
    if (cg < 63) {
      const unsigned short* g = eh + (size_t)((cg + 1) * 64 + co) * CD + seg * 64;
#pragma unroll
      for (int u = 0; u < 8; ++u) stg[u] = *(const uint4*)(g + u * 8);
    }
    __syncthreads();

    f32x4 acc[2][2];
#pragma unroll
    for (int mt = 0; mt < 2; ++mt)
#pragma unroll
      for (int nt = 0; nt < 2; ++nt) acc[mt][nt] = (f32x4){0.f, 0.f, 0.f, 0.f};

    const unsigned short* eb = &es[cg & 1][0];
#pragma unroll
    for (int kb = 0; kb < 8; ++kb) {
      const int c8 = (kb << 2) + lq;
#pragma unroll
      for (int nt = 0; nt < 2; ++nt) {
        const int col = ch32 + 16 * nt + ll;
        const bf16x8 bfr = *(const bf16x8*)&eb[(c8 * 64 + col) * 8];
        acc[0][nt] = __builtin_amdgcn_mfma_f32_16x16x32_bf16(afr[0][kb], bfr, acc[0][nt], 0, 0, 0);
        acc[1][nt] = __builtin_amdgcn_mfma_f32_16x16x32_bf16(afr[1][kb], bfr, acc[1][nt], 0, 0, 0);
      }
    }

    // epilogue: s' = se - 2*dot; update running min; tighten across row; collect
    float sv[2][2][4];
    float sev[2];
#pragma unroll
    for (int nt = 0; nt < 2; ++nt) sev[nt] = se[cg * 64 + ch32 + 16 * nt + ll];
#pragma unroll
    for (int nt = 0; nt < 2; ++nt)
#pragma unroll
      for (int mt = 0; mt < 2; ++mt)
#pragma unroll
        for (int r = 0; r < 4; ++r) {
          const float s = sev[nt] - 2.0f * acc[mt][nt][r];
          sv[nt][mt][r] = s;
          if (s < run[mt][r]) run[mt][r] = s;
        }
    float rr[2][4];
#pragma unroll
    for (int mt = 0; mt < 2; ++mt)
#pragma unroll
      for (int r = 0; r < 4; ++r) {
        float v = run[mt][r];
#pragma unroll
        for (int off = 1; off < 16; off <<= 1) v = fminf(v, __shfl_xor(v, off, 16));
        rr[mt][r] = v + WIN;
      }
#pragma unroll
    for (int nt = 0; nt < 2; ++nt)
#pragma unroll
      for (int mt = 0; mt < 2; ++mt)
#pragma unroll
        for (int r = 0; r < 4; ++r) {
          if (sv[nt][mt][r] <= rr[mt][r]) {
            const int row = rowbase + rs + 16 * mt + 4 * lq + r;
            const int code = cg * 64 + ch32 + 16 * nt + ll;
            const int pos = atomicAdd(&cnt[row], 1);
            if (pos < CAP) cand[(size_t)row * CAP + pos] = code;
          }
        }
    __syncthreads();
  }
}

// ---------- np-exact recheck of candidates (8 rows/block, 32 lanes/row) [verified] ----------
__global__ __launch_bounds__(256) void vq_recheck(const float* __restrict__ x,
                                                  const float* __restrict__ cb,
                                                  const float* __restrict__ se,
                                                  const int* __restrict__ cnt,
                                                  const int* __restrict__ cand,
                                                  float* __restrict__ outids,
                                                  int* __restrict__ flg,
                                                  int* __restrict__ nflg) {
#pragma clang fp contract(off)
  __shared__ float xr[8][256];
  __shared__ float sxs[8];
  const int t = threadIdx.x;
  const int r0 = blockIdx.x * 8;
  const int b = r0 >> 10, hw0 = r0 & 1023;
  {
    const float* px = x + ((size_t)b * CD + t) * HW + hw0;
    const float4 v0 = *(const float4*)(px);
    const float4 v1 = *(const float4*)(px + 4);
    xr[0][t] = v0.x; xr[1][t] = v0.y; xr[2][t] = v0.z; xr[3][t] = v0.w;
    xr[4][t] = v1.x; xr[5][t] = v1.y; xr[6][t] = v1.z; xr[7][t] = v1.w;
  }
  __syncthreads();
  if (t < 8) {   // np pairwise sx (verified order)
    float half[2];
#pragma unroll
    for (int h = 0; h < 2; ++h) {
      float racc[8];
#pragma unroll
      for (int j = 0; j < 8; ++j) { const float v = xr[t][h * 128 + j]; racc[j] = v * v; }
#pragma unroll
      for (int i = 1; i < 16; ++i)
#pragma unroll
        for (int j = 0; j < 8; ++j) {
          const float v = xr[t][h * 128 + 8 * i + j];
          const float v2 = v * v;
          racc[j] = racc[j] + v2;
        }
      half[h] = ((racc[0] + racc[1]) + (racc[2] + racc[3])) +
                ((racc[4] + racc[5]) + (racc[6] + racc[7]));
    }
    sxs[t] = half[0] + half[1];
  }
  __syncthreads();

  const int g = t >> 5, ln = t & 31;
  const int row = r0 + g;
  const int cn = cnt[row];
  float bv = FLT_MAX;
  int bi = 0x7FFFFFFF;
  if (cn > CAP) {
    if (ln == 0) { const int p = atomicAdd(nflg, 1); flg[p] = row; }
  } else {
    const float sx = sxs[g];
    const float* xrow = xr[g];
    for (int c = ln; c < cn; c += 32) {
      const int k = cand[(size_t)row * CAP + c];
      const float* ek = cb + (size_t)k * CD;
      float a0 = 0.f, a1 = 0.f, a2 = 0.f, a3 = 0.f;
      for (int B = 0; B < 16; ++B)
        for (int j = 3; j >= 0; --j) {
          const int c0 = 16 * B + 4 * j;
          float p0 = xrow[c0 + 0] * ek[c0 + 0]; a0 = a0 + p0;
          float p1 = xrow[c0 + 1] * ek[c0 + 1]; a1 = a1 + p1;
          float p2 = xrow[c0 + 2] * ek[c0 + 2]; a2 = a2 + p2;
          float p3 = xrow[c0 + 3] * ek[c0 + 3]; a3 = a3 + p3;
        }
      const float dot = (a0 + a1) + (a2 + a3);
      const float dist = (se[k] + sx) - 2.0f * dot;
      if (dist < bv || (dist == bv && k < bi)) { bv = dist; bi = k; }
    }
  }
#pragma unroll
  for (int off = 1; off < 32; off <<= 1) {
    const float ov = __shfl_xor(bv, off, 32);
    const int oi = __shfl_xor(bi, off, 32);
    if (ov < bv || (ov == bv && oi < bi)) { bv = ov; bi = oi; }
  }
  if (ln == 0 && cn <= CAP) outids[row] = (float)bi;
}

// ---------- full-row np-exact fallback for overflow rows [verified] ----------
__global__ __launch_bounds__(256) void vq_fallback(const float* __restrict__ x,
                                                   const float* __restrict__ cb,
                                                   const float* __restrict__ se,
                                                   const int* __restrict__ flg,
                                                   const int* __restrict__ nflg,
                                                   float* __restrict__ outids) {
#pragma clang fp contract(off)
  __shared__ float xr[256];
  __shared__ float sxv;
  __shared__ float rv[256];
  __shared__ int ri[256];
  const int t = threadIdx.x;
  const int nf = *nflg;
  for (int fi = blockIdx.x; fi < nf; fi += gridDim.x) {
    const int row = flg[fi];
    const int b = row >> 10, hw = row & 1023;
    __syncthreads();
    xr[t] = x[((size_t)b * CD + t) * HW + hw];
    __syncthreads();
    if (t == 0) {
      float half[2];
      for (int h = 0; h < 2; ++h) {
        float racc[8];
        for (int j = 0; j < 8; ++j) { const float v = xr[h * 128 + j]; racc[j] = v * v; }
        for (int i = 1; i < 16; ++i)
          for (int j = 0; j < 8; ++j) {
            const float v = xr[h * 128 + 8 * i + j];
            const float v2 = v * v;
            racc[j] = racc[j] + v2;
          }
        half[h] = ((racc[0] + racc[1]) + (racc[2] + racc[3])) +
                  ((racc[4] + racc[5]) + (racc[6] + racc[7]));
      }
      sxv = half[0] + half[1];
    }
    __syncthreads();
    float bv = FLT_MAX;
    int bi = 0x7FFFFFFF;
    for (int j = 0; j < 16; ++j) {
      const int k = j * 256 + t;
      const float* ek = cb + (size_t)k * CD;
      float a0 = 0.f, a1 = 0.f, a2 = 0.f, a3 = 0.f;
      for (int B = 0; B < 16; ++B)
        for (int jj = 3; jj >= 0; --jj) {
          const int c0 = 16 * B + 4 * jj;
          float p0 = xr[c0 + 0] * ek[c0 + 0]; a0 = a0 + p0;
          float p1 = xr[c0 + 1] * ek[c0 + 1]; a1 = a1 + p1;
          float p2 = xr[c0 + 2] * ek[c0 + 2]; a2 = a2 + p2;
          float p3 = xr[c0 + 3] * ek[c0 + 3]; a3 = a3 + p3;
        }
      const float dot = (a0 + a1) + (a2 + a3);
      const float dist = (se[k] + sxv) - 2.0f * dot;
      if (dist < bv || (dist == bv && k < bi)) { bv = dist; bi = k; }
    }
    rv[t] = bv; ri[t] = bi;
    __syncthreads();
    for (int off = 128; off > 0; off >>= 1) {
      if (t < off) {
        if (rv[t + off] < rv[t] || (rv[t + off] == rv[t] && ri[t + off] < ri[t])) {
          rv[t] = rv[t + off]; ri[t] = ri[t + off];
        }
      }
      __syncthreads();
    }
    if (t == 0) outids[row] = (float)ri[0];
  }
}

// ---------- emb gather [verified] ----------
__global__ __launch_bounds__(256) void vq_emb_out(const float* __restrict__ outids,
                                                  const float* __restrict__ cb,
                                                  float* __restrict__ out) {
  const int bx = blockIdx.x;
  const int b = bx >> 10;
  const int rem = bx & 1023;
  const int c = rem >> 2;
  const int q = rem & 3;
  const int hw = q * 256 + threadIdx.x;
  const int id = (int)outids[b * HW + hw];
  out[((size_t)(b * CD + c)) * HW + hw] = cb[(size_t)id * CD + c];
}

extern "C" void kernel_launch(void* const* d_in, const int* in_sizes, int n_in,
                              void* d_out, int out_size, void* d_ws, size_t ws_size,
                              hipStream_t stream) {
  const float* x  = (const float*)d_in[0];   // (32,256,32,32) f32
  const float* cb = (const float*)d_in[1];   // (4096,256) f32
  float* out = (float*)d_out;                // [0..32767]=ids, [32768..]=emb

  float* se = (float*)d_ws;                  // 16 KB

  // scratch inside the emb region (8,388,608 floats), overwritten last by gather
  float* sc = out + NRW;
  unsigned short* xh = (unsigned short*)sc;              // 16.8 MB
  unsigned short* eh = (unsigned short*)(sc + 4194304);  // 2.1 MB
  int*   cnt  = (int*)(sc + 4751360);                    // 32,768
  int*   flg  = (int*)(sc + 4784128);                    // 32,768
  int*   nflg = (int*)(sc + 4816896);                    // 1
  int*   cand = (int*)(sc + 4816960);                    // 32768*64 ints

  vq_se<<<KC / 32, 256, 0, stream>>>(cb, se);
  vq_cvt_x<<<512, 256, 0, stream>>>(x, xh);
  vq_cvt_e<<<1024, 256, 0, stream>>>(cb, eh);
  vq_init<<<128, 256, 0, stream>>>(cnt, nflg);
  vq_gemm<<<512, 256, 0, stream>>>(xh, eh, se, cnt, cand);
  vq_recheck<<<NRW / 8, 256, 0, stream>>>(x, cb, se, cnt, cand, out, flg, nflg);
  vq_fallback<<<512, 256, 0, stream>>>(x, cb, se, flg, nflg, out);
  vq_emb_out<<<32768, 256, 0, stream>>>(out, cb, out + NRW);
}

// Round 16
// 624.773 us; speedup vs baseline: 1.0920x; 1.0920x over previous
//
#include <hip/hip_runtime.h>
#include <cfloat>

#define NRW 32768
#define KC 4096
#define CD 256
#define HW 1024
#define CAP 64
#define WIN 1e-3f

typedef short bf16x8 __attribute__((ext_vector_type(8)));
typedef float f32x4 __attribute__((ext_vector_type(4)));

__device__ __forceinline__ unsigned short f2bf(float f) {  // RNE f32->bf16
  unsigned int u = __float_as_uint(f);
  u = (u + 0x7FFFu + ((u >> 16) & 1u)) >> 16;
  return (unsigned short)u;
}

// min across each 16-lane DPP row, pure VALU (no LDS traffic)
__device__ __forceinline__ float dppmin16(float v) {
  float t;
  t = __uint_as_float(__builtin_amdgcn_update_dpp(0, __float_as_uint(v), 0xB1, 0xF, 0xF, true));  // xor1
  v = fminf(v, t);
  t = __uint_as_float(__builtin_amdgcn_update_dpp(0, __float_as_uint(v), 0x4E, 0xF, 0xF, true));  // xor2
  v = fminf(v, t);
  t = __uint_as_float(__builtin_amdgcn_update_dpp(0, __float_as_uint(v), 0x141, 0xF, 0xF, true)); // xor4 (half mirror)
  v = fminf(v, t);
  t = __uint_as_float(__builtin_amdgcn_update_dpp(0, __float_as_uint(v), 0x140, 0xF, 0xF, true)); // xor8 (mirror)
  v = fminf(v, t);
  return v;
}

// ---------- se[k] = np.sum(cb[k]**2) : numpy pairwise (128+128, scalar 8-acc) [verified] ----------
__global__ __launch_bounds__(256) void vq_se(const float* __restrict__ cb,
                                             float* __restrict__ se) {
#pragma clang fp contract(off)
  const int tid = threadIdx.x;
  const int g = tid >> 3;
  const int j = tid & 7;
  const int code = blockIdx.x * 32 + g;
  const float* e = cb + (size_t)code * CD;
  float half[2];
#pragma unroll
  for (int h = 0; h < 2; ++h) {
    const float* a = e + h * 128;
    float v = a[j];
    float r = v * v;
#pragma unroll
    for (int i = 1; i < 16; ++i) {
      float w = a[8 * i + j];
      float w2 = w * w;
      r = r + w2;
    }
    float l1 = r + __shfl_down(r, 1, 8);
    float l2 = l1 + __shfl_down(l1, 2, 8);
    float l3 = l2 + __shfl_down(l2, 4, 8);
    half[h] = l3;
  }
  if (j == 0) se[code] = half[0] + half[1];
}

// ---------- convert x (B,C,H,W) f32 -> xh[row][ch] bf16 (transpose, RNE) [verified] ----------
__global__ __launch_bounds__(256) void vq_cvt_x(const float* __restrict__ x,
                                                unsigned short* __restrict__ xh) {
  const int t = threadIdx.x;                  // channel
  const int b = blockIdx.x >> 4;
  const int hw0 = (blockIdx.x & 15) << 6;
  const float* src = x + ((size_t)b * CD + t) * HW + hw0;
  unsigned short* dst = xh + ((size_t)b * HW + hw0) * CD + t;
#pragma unroll
  for (int f = 0; f < 16; ++f) {
    const float4 v = *(const float4*)(src + 4 * f);
    dst[(size_t)(4 * f + 0) * CD] = f2bf(v.x);
    dst[(size_t)(4 * f + 1) * CD] = f2bf(v.y);
    dst[(size_t)(4 * f + 2) * CD] = f2bf(v.z);
    dst[(size_t)(4 * f + 3) * CD] = f2bf(v.w);
  }
}

// ---------- convert cb f32 -> eh bf16 (flat) [verified] ----------
__global__ __launch_bounds__(256) void vq_cvt_e(const float* __restrict__ cb,
                                                unsigned short* __restrict__ eh) {
  const int i4 = (blockIdx.x * 256 + threadIdx.x) * 4;
  const float4 v = *(const float4*)(cb + i4);
  ushort4 o;
  o.x = f2bf(v.x); o.y = f2bf(v.y); o.z = f2bf(v.z); o.w = f2bf(v.w);
  *(ushort4*)(eh + i4) = o;
}

// ---------- zero cnt + nflg ----------
__global__ __launch_bounds__(256) void vq_init(int* __restrict__ cnt,
                                               int* __restrict__ nflg) {
  const int i = blockIdx.x * 256 + threadIdx.x;
  cnt[i] = 0;
  if (i == 0) *nflg = 0;
}

// ---------- single-pass MFMA filter GEMM, conflict-free XOR-granule LDS ----------
// 64 rows/block; wave w: rows (w&1)*32..+32 (two 16-slabs), code half (w>>1)*32.
// es granule (c8, code) stored at granule index c8*64 + (code ^ (c8&7)).
__global__ __launch_bounds__(256) void vq_gemm(const unsigned short* __restrict__ xh,
                                               const unsigned short* __restrict__ eh,
                                               const float* __restrict__ se,
                                               int* __restrict__ cnt,
                                               int* __restrict__ cand) {
  __shared__ unsigned short es[2][64 * 256];  // 2 x 32 KB double buffer

  const int t = threadIdx.x;
  const int l = t & 63;
  const int w = t >> 6;
  const int rs = (w & 1) * 32;                // row-slab base within block
  const int ch32 = (w >> 1) * 32;             // code half within cg
  const int rowbase = blockIdx.x * 64;
  const int lq = l >> 4;                      // lane quad 0..3
  const int ll = l & 15;

  // A fragments: 2 slabs x 8 kb, direct from global (resident)
  bf16x8 afr[2][8];
#pragma unroll
  for (int mt = 0; mt < 2; ++mt) {
    const unsigned short* ga = xh + (size_t)(rowbase + rs + 16 * mt + ll) * CD + (lq << 3);
#pragma unroll
    for (int kb = 0; kb < 8; ++kb)
      afr[mt][kb] = *(const bf16x8*)(ga + (kb << 5));
  }

  float run[2][4];
#pragma unroll
  for (int mt = 0; mt < 2; ++mt)
#pragma unroll
    for (int r = 0; r < 4; ++r) run[mt][r] = FLT_MAX;

  // staging map: step u, thread t -> code_local = u*8 + (t>>5), granule g = t&31
  const int sg = t & 31, c0 = t >> 5;
  const int srcbase = c0 * 256 + sg * 8;
  int dsto[8];
#pragma unroll
  for (int u = 0; u < 8; ++u)
    dsto[u] = (sg * 64 + ((u * 8 + c0) ^ (sg & 7))) * 8;

  uint4 stg[8];
#pragma unroll
  for (int u = 0; u < 8; ++u) stg[u] = *(const uint4*)(eh + u * 2048 + srcbase);        // chunk 0
#pragma unroll
  for (int u = 0; u < 8; ++u) *(uint4*)&es[0][dsto[u]] = stg[u];                        // publish 0
#pragma unroll
  for (int u = 0; u < 8; ++u) stg[u] = *(const uint4*)(eh + 16384 + u * 2048 + srcbase); // chunk 1
  __syncthreads();

#pragma unroll 1
  for (int cg = 0; cg < 64; ++cg) {
    // publish chunk cg+1 (regs) into the other buffer; prefetch chunk cg+2
    if (cg < 63) {
      unsigned short* d = &es[(cg + 1) & 1][0];
#pragma unroll
      for (int u = 0; u < 8; ++u) *(uint4*)&d[dsto[u]] = stg[u];
    }
    if (cg < 62) {
      const unsigned short* g = eh + (size_t)(cg + 2) * 16384 + srcbase;
#pragma unroll
      for (int u = 0; u < 8; ++u) stg[u] = *(const uint4*)(g + u * 2048);
    }

    // compute chunk cg
    f32x4 acc[2][2];
#pragma unroll
    for (int mt = 0; mt < 2; ++mt)
#pragma unroll
      for (int nt = 0; nt < 2; ++nt) acc[mt][nt] = (f32x4){0.f, 0.f, 0.f, 0.f};

    const unsigned short* eb = &es[cg & 1][0];
#pragma unroll
    for (int kb = 0; kb < 8; ++kb) {
      const int c8 = (kb << 2) + lq;
#pragma unroll
      for (int nt = 0; nt < 2; ++nt) {
        const int col = ch32 + 16 * nt + ll;
        const bf16x8 bfr = *(const bf16x8*)&eb[(c8 * 64 + (col ^ (c8 & 7))) * 8];
        acc[0][nt] = __builtin_amdgcn_mfma_f32_16x16x32_bf16(afr[0][kb], bfr, acc[0][nt], 0, 0, 0);
        acc[1][nt] = __builtin_amdgcn_mfma_f32_16x16x32_bf16(afr[1][kb], bfr, acc[1][nt], 0, 0, 0);
      }
    }

    // epilogue: s' = se - 2*dot; running min; DPP row-tighten; collect
    float sv[2][2][4];
    float sev[2];
#pragma unroll
    for (int nt = 0; nt < 2; ++nt) sev[nt] = se[cg * 64 + ch32 + 16 * nt + ll];
#pragma unroll
    for (int nt = 0; nt < 2; ++nt)
#pragma unroll
      for (int mt = 0; mt < 2; ++mt)
#pragma unroll
        for (int r = 0; r < 4; ++r) {
          const float s = sev[nt] - 2.0f * acc[mt][nt][r];
          sv[nt][mt][r] = s;
          if (s < run[mt][r]) run[mt][r] = s;
        }
    float rr[2][4];
#pragma unroll
    for (int mt = 0; mt < 2; ++mt)
#pragma unroll
      for (int r = 0; r < 4; ++r)
        rr[mt][r] = dppmin16(run[mt][r]) + WIN;
#pragma unroll
    for (int nt = 0; nt < 2; ++nt)
#pragma unroll
      for (int mt = 0; mt < 2; ++mt)
#pragma unroll
        for (int r = 0; r < 4; ++r) {
          if (sv[nt][mt][r] <= rr[mt][r]) {
            const int row = rowbase + rs + 16 * mt + 4 * lq + r;
            const int code = cg * 64 + ch32 + 16 * nt + ll;
            const int pos = atomicAdd(&cnt[row], 1);
            if (pos < CAP) cand[(size_t)row * CAP + pos] = code;
          }
        }
    __syncthreads();
  }
}

// ---------- np-exact recheck of candidates (8 rows/block, 32 lanes/row) [verified] ----------
__global__ __launch_bounds__(256) void vq_recheck(const float* __restrict__ x,
                                                  const float* __restrict__ cb,
                                                  const float* __restrict__ se,
                                                  const int* __restrict__ cnt,
                                                  const int* __restrict__ cand,
                                                  float* __restrict__ outids,
                                                  int* __restrict__ flg,
                                                  int* __restrict__ nflg) {
#pragma clang fp contract(off)
  __shared__ float xr[8][256];
  __shared__ float sxs[8];
  const int t = threadIdx.x;
  const int r0 = blockIdx.x * 8;
  const int b = r0 >> 10, hw0 = r0 & 1023;
  {
    const float* px = x + ((size_t)b * CD + t) * HW + hw0;
    const float4 v0 = *(const float4*)(px);
    const float4 v1 = *(const float4*)(px + 4);
    xr[0][t] = v0.x; xr[1][t] = v0.y; xr[2][t] = v0.z; xr[3][t] = v0.w;
    xr[4][t] = v1.x; xr[5][t] = v1.y; xr[6][t] = v1.z; xr[7][t] = v1.w;
  }
  __syncthreads();
  if (t < 8) {   // np pairwise sx (verified order)
    float half[2];
#pragma unroll
    for (int h = 0; h < 2; ++h) {
      float racc[8];
#pragma unroll
      for (int j = 0; j < 8; ++j) { const float v = xr[t][h * 128 + j]; racc[j] = v * v; }
#pragma unroll
      for (int i = 1; i < 16; ++i)
#pragma unroll
        for (int j = 0; j < 8; ++j) {
          const float v = xr[t][h * 128 + 8 * i + j];
          const float v2 = v * v;
          racc[j] = racc[j] + v2;
        }
      half[h] = ((racc[0] + racc[1]) + (racc[2] + racc[3])) +
                ((racc[4] + racc[5]) + (racc[6] + racc[7]));
    }
    sxs[t] = half[0] + half[1];
  }
  __syncthreads();

  const int g = t >> 5, ln = t & 31;
  const int row = r0 + g;
  const int cn = cnt[row];
  float bv = FLT_MAX;
  int bi = 0x7FFFFFFF;
  if (cn > CAP) {
    if (ln == 0) { const int p = atomicAdd(nflg, 1); flg[p] = row; }
  } else {
    const float sx = sxs[g];
    const float* xrow = xr[g];
    for (int c = ln; c < cn; c += 32) {
      const int k = cand[(size_t)row * CAP + c];
      const float* ek = cb + (size_t)k * CD;
      float a0 = 0.f, a1 = 0.f, a2 = 0.f, a3 = 0.f;
      for (int B = 0; B < 16; ++B)
        for (int j = 3; j >= 0; --j) {
          const int c0 = 16 * B + 4 * j;
          float p0 = xrow[c0 + 0] * ek[c0 + 0]; a0 = a0 + p0;
          float p1 = xrow[c0 + 1] * ek[c0 + 1]; a1 = a1 + p1;
          float p2 = xrow[c0 + 2] * ek[c0 + 2]; a2 = a2 + p2;
          float p3 = xrow[c0 + 3] * ek[c0 + 3]; a3 = a3 + p3;
        }
      const float dot = (a0 + a1) + (a2 + a3);
      const float dist = (se[k] + sx) - 2.0f * dot;
      if (dist < bv || (dist == bv && k < bi)) { bv = dist; bi = k; }
    }
  }
#pragma unroll
  for (int off = 1; off < 32; off <<= 1) {
    const float ov = __shfl_xor(bv, off, 32);
    const int oi = __shfl_xor(bi, off, 32);
    if (ov < bv || (ov == bv && oi < bi)) { bv = ov; bi = oi; }
  }
  if (ln == 0 && cn <= CAP) outids[row] = (float)bi;
}

// ---------- full-row np-exact fallback for overflow rows [verified] ----------
__global__ __launch_bounds__(256) void vq_fallback(const float* __restrict__ x,
                                                   const float* __restrict__ cb,
                                                   const float* __restrict__ se,
                                                   const int* __restrict__ flg,
                                                   const int* __restrict__ nflg,
                                                   float* __restrict__ outids) {
#pragma clang fp contract(off)
  __shared__ float xr[256];
  __shared__ float sxv;
  __shared__ float rv[256];
  __shared__ int ri[256];
  const int t = threadIdx.x;
  const int nf = *nflg;
  for (int fi = blockIdx.x; fi < nf; fi += gridDim.x) {
    const int row = flg[fi];
    const int b = row >> 10, hw = row & 1023;
    __syncthreads();
    xr[t] = x[((size_t)b * CD + t) * HW + hw];
    __syncthreads();
    if (t == 0) {
      float half[2];
      for (int h = 0; h < 2; ++h) {
        float racc[8];
        for (int j = 0; j < 8; ++j) { const float v = xr[h * 128 + j]; racc[j] = v * v; }
        for (int i = 1; i < 16; ++i)
          for (int j = 0; j < 8; ++j) {
            const float v = xr[h * 128 + 8 * i + j];
            const float v2 = v * v;
            racc[j] = racc[j] + v2;
          }
        half[h] = ((racc[0] + racc[1]) + (racc[2] + racc[3])) +
                  ((racc[4] + racc[5]) + (racc[6] + racc[7]));
      }
      sxv = half[0] + half[1];
    }
    __syncthreads();
    float bv = FLT_MAX;
    int bi = 0x7FFFFFFF;
    for (int j = 0; j < 16; ++j) {
      const int k = j * 256 + t;
      const float* ek = cb + (size_t)k * CD;
      float a0 = 0.f, a1 = 0.f, a2 = 0.f, a3 = 0.f;
      for (int B = 0; B < 16; ++B)
        for (int jj = 3; jj >= 0; --jj) {
          const int c0 = 16 * B + 4 * jj;
          float p0 = xr[c0 + 0] * ek[c0 + 0]; a0 = a0 + p0;
          float p1 = xr[c0 + 1] * ek[c0 + 1]; a1 = a1 + p1;
          float p2 = xr[c0 + 2] * ek[c0 + 2]; a2 = a2 + p2;
          float p3 = xr[c0 + 3] * ek[c0 + 3]; a3 = a3 + p3;
        }
      const float dot = (a0 + a1) + (a2 + a3);
      const float dist = (se[k] + sxv) - 2.0f * dot;
      if (dist < bv || (dist == bv && k < bi)) { bv = dist; bi = k; }
    }
    rv[t] = bv; ri[t] = bi;
    __syncthreads();
    for (int off = 128; off > 0; off >>= 1) {
      if (t < off) {
        if (rv[t + off] < rv[t] || (rv[t + off] == rv[t] && ri[t + off] < ri[t])) {
          rv[t] = rv[t + off]; ri[t] = ri[t + off];
        }
      }
      __syncthreads();
    }
    if (t == 0) outids[row] = (float)ri[0];
  }
}

// ---------- emb gather [verified] ----------
__global__ __launch_bounds__(256) void vq_emb_out(const float* __restrict__ outids,
                                                  const float* __restrict__ cb,
                                                  float* __restrict__ out) {
  const int bx = blockIdx.x;
  const int b = bx >> 10;
  const int rem = bx & 1023;
  const int c = rem >> 2;
  const int q = rem & 3;
  const int hw = q * 256 + threadIdx.x;
  const int id = (int)outids[b * HW + hw];
  out[((size_t)(b * CD + c)) * HW + hw] = cb[(size_t)id * CD + c];
}

extern "C" void kernel_launch(void* const* d_in, const int* in_sizes, int n_in,
                              void* d_out, int out_size, void* d_ws, size_t ws_size,
                              hipStream_t stream) {
  const float* x  = (const float*)d_in[0];   // (32,256,32,32) f32
  const float* cb = (const float*)d_in[1];   // (4096,256) f32
  float* out = (float*)d_out;                // [0..32767]=ids, [32768..]=emb

  float* se = (float*)d_ws;                  // 16 KB

  // scratch inside the emb region (8,388,608 floats), overwritten last by gather
  float* sc = out + NRW;
  unsigned short* xh = (unsigned short*)sc;              // 16.8 MB
  unsigned short* eh = (unsigned short*)(sc + 4194304);  // 2.1 MB
  int*   cnt  = (int*)(sc + 4751360);                    // 32,768
  int*   flg  = (int*)(sc + 4784128);                    // 32,768
  int*   nflg = (int*)(sc + 4816896);                    // 1
  int*   cand = (int*)(sc + 4816960);                    // 32768*64 ints

  vq_se<<<KC / 32, 256, 0, stream>>>(cb, se);
  vq_cvt_x<<<512, 256, 0, stream>>>(x, xh);
  vq_cvt_e<<<1024, 256, 0, stream>>>(cb, eh);
  vq_init<<<128, 256, 0, stream>>>(cnt, nflg);
  vq_gemm<<<512, 256, 0, stream>>>(xh, eh, se, cnt, cand);
  vq_recheck<<<NRW / 8, 256, 0, stream>>>(x, cb, se, cnt, cand, out, flg, nflg);
  vq_fallback<<<512, 256, 0, stream>>>(x, cb, se, flg, nflg, out);
  vq_emb_out<<<32768, 256, 0, stream>>>(out, cb, out + NRW);
}

// Round 17
// 437.953 us; speedup vs baseline: 1.5579x; 1.4266x over previous
//
#include <hip/hip_runtime.h>
#include <cfloat>

#define NRW 32768
#define KC 4096
#define CD 256
#define HW 1024
#define CAP 64
#define WIN 1e-3f

typedef short bf16x8 __attribute__((ext_vector_type(8)));
typedef float f32x4 __attribute__((ext_vector_type(4)));

__device__ __forceinline__ unsigned short f2bf(float f) {  // RNE f32->bf16
  unsigned int u = __float_as_uint(f);
  u = (u + 0x7FFFu + ((u >> 16) & 1u)) >> 16;
  return (unsigned short)u;
}

// direct global->LDS 16B async copy: lds dest = uniform base + lane*16
__device__ __forceinline__ void gl2lds16(const unsigned short* g, unsigned short* l) {
  __builtin_amdgcn_global_load_lds(
      (const __attribute__((address_space(1))) void*)(const void*)g,
      (__attribute__((address_space(3))) void*)(void*)l, 16, 0, 0);
}

// min across each 16-lane DPP row, pure VALU (no LDS traffic) [verified r16]
__device__ __forceinline__ float dppmin16(float v) {
  float t;
  t = __uint_as_float(__builtin_amdgcn_update_dpp(0, __float_as_uint(v), 0xB1, 0xF, 0xF, true));
  v = fminf(v, t);
  t = __uint_as_float(__builtin_amdgcn_update_dpp(0, __float_as_uint(v), 0x4E, 0xF, 0xF, true));
  v = fminf(v, t);
  t = __uint_as_float(__builtin_amdgcn_update_dpp(0, __float_as_uint(v), 0x141, 0xF, 0xF, true));
  v = fminf(v, t);
  t = __uint_as_float(__builtin_amdgcn_update_dpp(0, __float_as_uint(v), 0x140, 0xF, 0xF, true));
  v = fminf(v, t);
  return v;
}

// ---------- se[k] = np.sum(cb[k]**2) : numpy pairwise (128+128, scalar 8-acc) [verified] ----------
__global__ __launch_bounds__(256) void vq_se(const float* __restrict__ cb,
                                             float* __restrict__ se) {
#pragma clang fp contract(off)
  const int tid = threadIdx.x;
  const int g = tid >> 3;
  const int j = tid & 7;
  const int code = blockIdx.x * 32 + g;
  const float* e = cb + (size_t)code * CD;
  float half[2];
#pragma unroll
  for (int h = 0; h < 2; ++h) {
    const float* a = e + h * 128;
    float v = a[j];
    float r = v * v;
#pragma unroll
    for (int i = 1; i < 16; ++i) {
      float w = a[8 * i + j];
      float w2 = w * w;
      r = r + w2;
    }
    float l1 = r + __shfl_down(r, 1, 8);
    float l2 = l1 + __shfl_down(l1, 2, 8);
    float l3 = l2 + __shfl_down(l2, 4, 8);
    half[h] = l3;
  }
  if (j == 0) se[code] = half[0] + half[1];
}

// ---------- convert x (B,C,H,W) f32 -> xh[row][ch] bf16 (transpose, RNE) [verified] ----------
__global__ __launch_bounds__(256) void vq_cvt_x(const float* __restrict__ x,
                                                unsigned short* __restrict__ xh) {
  const int t = threadIdx.x;                  // channel
  const int b = blockIdx.x >> 4;
  const int hw0 = (blockIdx.x & 15) << 6;
  const float* src = x + ((size_t)b * CD + t) * HW + hw0;
  unsigned short* dst = xh + ((size_t)b * HW + hw0) * CD + t;
#pragma unroll
  for (int f = 0; f < 16; ++f) {
    const float4 v = *(const float4*)(src + 4 * f);
    dst[(size_t)(4 * f + 0) * CD] = f2bf(v.x);
    dst[(size_t)(4 * f + 1) * CD] = f2bf(v.y);
    dst[(size_t)(4 * f + 2) * CD] = f2bf(v.z);
    dst[(size_t)(4 * f + 3) * CD] = f2bf(v.w);
  }
}

// ---------- convert cb f32 -> eh PRE-SWIZZLED granule layout ----------
// granule gid = ((cg*32 + c8)*64 + m): holds code cg*64 + (m ^ (c8&7)), channels [c8*8, +8)
__global__ __launch_bounds__(256) void vq_cvt_e(const float* __restrict__ cb,
                                                unsigned short* __restrict__ eh) {
  const int gid = blockIdx.x * 256 + threadIdx.x;   // 131072 granules
  const int cg = gid >> 11;
  const int c8 = (gid >> 6) & 31;
  const int m  = gid & 63;
  const int code = (cg << 6) | (m ^ (c8 & 7));
  const float* s = cb + (size_t)code * CD + (c8 << 3);
  uint4 v;
  v.x = (unsigned)f2bf(s[0]) | ((unsigned)f2bf(s[1]) << 16);
  v.y = (unsigned)f2bf(s[2]) | ((unsigned)f2bf(s[3]) << 16);
  v.z = (unsigned)f2bf(s[4]) | ((unsigned)f2bf(s[5]) << 16);
  v.w = (unsigned)f2bf(s[6]) | ((unsigned)f2bf(s[7]) << 16);
  *(uint4*)(eh + (size_t)gid * 8) = v;
}

// ---------- zero cnt + nflg ----------
__global__ __launch_bounds__(256) void vq_init(int* __restrict__ cnt,
                                               int* __restrict__ nflg) {
  const int i = blockIdx.x * 256 + threadIdx.x;
  cnt[i] = 0;
  if (i == 0) *nflg = 0;
}

// ---------- single-pass MFMA filter GEMM: async global->LDS, no staging regs ----------
// 64 rows/block; wave w: rows (w&1)*32..+32 (two 16-slabs), code half (w>>1)*32.
// es granule (c8, m) at granule index c8*64 + m; eh is pre-swizzled so m holds code m^(c8&7).
__global__ __launch_bounds__(256, 2) void vq_gemm(const unsigned short* __restrict__ xh,
                                                  const unsigned short* __restrict__ eh,
                                                  const float* __restrict__ se,
                                                  int* __restrict__ cnt,
                                                  int* __restrict__ cand) {
  __shared__ unsigned short es[2][64 * 256];  // 2 x 32 KB double buffer

  const int t = threadIdx.x;
  const int l = t & 63;
  const int w = t >> 6;
  const int rs = (w & 1) * 32;                // row-slab base within block
  const int ch32 = (w >> 1) * 32;             // code half within cg
  const int rowbase = blockIdx.x * 64;
  const int lq = l >> 4;                      // lane quad 0..3
  const int ll = l & 15;
  const int c8b = w << 3;                     // this wave stages c8 in [8w, 8w+8)

  // A fragments: 2 slabs x 8 kb, direct from global (resident)
  bf16x8 afr[2][8];
#pragma unroll
  for (int mt = 0; mt < 2; ++mt) {
    const unsigned short* ga = xh + (size_t)(rowbase + rs + 16 * mt + ll) * CD + (lq << 3);
#pragma unroll
    for (int kb = 0; kb < 8; ++kb)
      afr[mt][kb] = *(const bf16x8*)(ga + (kb << 5));
  }

  float run[2][4];
#pragma unroll
  for (int mt = 0; mt < 2; ++mt)
#pragma unroll
    for (int r = 0; r < 4; ++r) run[mt][r] = FLT_MAX;

  // prologue: stage chunk 0 into es[0] (async, lane-contiguous source)
#pragma unroll
  for (int i = 0; i < 8; ++i) {
    const int c8 = c8b + i;
    gl2lds16(eh + ((size_t)c8 * 64 + l) * 8, &es[0][c8 << 9]);
  }
  __syncthreads();

#pragma unroll 1
  for (int cg = 0; cg < 64; ++cg) {
    // issue async staging of chunk cg+1 into the other buffer (overlaps compute)
    if (cg < 63) {
      const size_t cbase = (size_t)(cg + 1) * 2048;   // granules per chunk = 32*64
      unsigned short* db = &es[(cg + 1) & 1][0];
#pragma unroll
      for (int i = 0; i < 8; ++i) {
        const int c8 = c8b + i;
        gl2lds16(eh + (cbase + (size_t)c8 * 64 + l) * 8, &db[c8 << 9]);
      }
    }

    // compute chunk cg
    f32x4 acc[2][2];
#pragma unroll
    for (int mt = 0; mt < 2; ++mt)
#pragma unroll
      for (int nt = 0; nt < 2; ++nt) acc[mt][nt] = (f32x4){0.f, 0.f, 0.f, 0.f};

    const unsigned short* eb = &es[cg & 1][0];
#pragma unroll
    for (int kb = 0; kb < 8; ++kb) {
      const int c8 = (kb << 2) + lq;
#pragma unroll
      for (int nt = 0; nt < 2; ++nt) {
        const int col = ch32 + 16 * nt + ll;
        const bf16x8 bfr = *(const bf16x8*)&eb[(c8 * 64 + (col ^ (c8 & 7))) * 8];
        acc[0][nt] = __builtin_amdgcn_mfma_f32_16x16x32_bf16(afr[0][kb], bfr, acc[0][nt], 0, 0, 0);
        acc[1][nt] = __builtin_amdgcn_mfma_f32_16x16x32_bf16(afr[1][kb], bfr, acc[1][nt], 0, 0, 0);
      }
    }

    // epilogue: s' = se - 2*dot; running min; DPP row-tighten; collect
    float sv[2][2][4];
    float sev[2];
#pragma unroll
    for (int nt = 0; nt < 2; ++nt) sev[nt] = se[cg * 64 + ch32 + 16 * nt + ll];
#pragma unroll
    for (int nt = 0; nt < 2; ++nt)
#pragma unroll
      for (int mt = 0; mt < 2; ++mt)
#pragma unroll
        for (int r = 0; r < 4; ++r) {
          const float s = sev[nt] - 2.0f * acc[mt][nt][r];
          sv[nt][mt][r] = s;
          if (s < run[mt][r]) run[mt][r] = s;
        }
    float rr[2][4];
#pragma unroll
    for (int mt = 0; mt < 2; ++mt)
#pragma unroll
      for (int r = 0; r < 4; ++r)
        rr[mt][r] = dppmin16(run[mt][r]) + WIN;
#pragma unroll
    for (int nt = 0; nt < 2; ++nt)
#pragma unroll
      for (int mt = 0; mt < 2; ++mt)
#pragma unroll
        for (int r = 0; r < 4; ++r) {
          if (sv[nt][mt][r] <= rr[mt][r]) {
            const int row = rowbase + rs + 16 * mt + 4 * lq + r;
            const int code = cg * 64 + ch32 + 16 * nt + ll;
            const int pos = atomicAdd(&cnt[row], 1);
            if (pos < CAP) cand[(size_t)row * CAP + pos] = code;
          }
        }
    __syncthreads();   // drains vmcnt -> staged chunk cg+1 visible; es[cg&1] free
  }
}

// ---------- np-exact recheck of candidates (8 rows/block, 32 lanes/row) [verified] ----------
__global__ __launch_bounds__(256) void vq_recheck(const float* __restrict__ x,
                                                  const float* __restrict__ cb,
                                                  const float* __restrict__ se,
                                                  const int* __restrict__ cnt,
                                                  const int* __restrict__ cand,
                                                  float* __restrict__ outids,
                                                  int* __restrict__ flg,
                                                  int* __restrict__ nflg) {
#pragma clang fp contract(off)
  __shared__ float xr[8][256];
  __shared__ float sxs[8];
  const int t = threadIdx.x;
  const int r0 = blockIdx.x * 8;
  const int b = r0 >> 10, hw0 = r0 & 1023;
  {
    const float* px = x + ((size_t)b * CD + t) * HW + hw0;
    const float4 v0 = *(const float4*)(px);
    const float4 v1 = *(const float4*)(px + 4);
    xr[0][t] = v0.x; xr[1][t] = v0.y; xr[2][t] = v0.z; xr[3][t] = v0.w;
    xr[4][t] = v1.x; xr[5][t] = v1.y; xr[6][t] = v1.z; xr[7][t] = v1.w;
  }
  __syncthreads();
  if (t < 8) {   // np pairwise sx (verified order)
    float half[2];
#pragma unroll
    for (int h = 0; h < 2; ++h) {
      float racc[8];
#pragma unroll
      for (int j = 0; j < 8; ++j) { const float v = xr[t][h * 128 + j]; racc[j] = v * v; }
#pragma unroll
      for (int i = 1; i < 16; ++i)
#pragma unroll
        for (int j = 0; j < 8; ++j) {
          const float v = xr[t][h * 128 + 8 * i + j];
          const float v2 = v * v;
          racc[j] = racc[j] + v2;
        }
      half[h] = ((racc[0] + racc[1]) + (racc[2] + racc[3])) +
                ((racc[4] + racc[5]) + (racc[6] + racc[7]));
    }
    sxs[t] = half[0] + half[1];
  }
  __syncthreads();

  const int g = t >> 5, ln = t & 31;
  const int row = r0 + g;
  const int cn = cnt[row];
  float bv = FLT_MAX;
  int bi = 0x7FFFFFFF;
  if (cn > CAP) {
    if (ln == 0) { const int p = atomicAdd(nflg, 1); flg[p] = row; }
  } else {
    const float sx = sxs[g];
    const float* xrow = xr[g];
    for (int c = ln; c < cn; c += 32) {
      const int k = cand[(size_t)row * CAP + c];
      const float* ek = cb + (size_t)k * CD;
      float a0 = 0.f, a1 = 0.f, a2 = 0.f, a3 = 0.f;
      for (int B = 0; B < 16; ++B)
        for (int j = 3; j >= 0; --j) {
          const int c0 = 16 * B + 4 * j;
          float p0 = xrow[c0 + 0] * ek[c0 + 0]; a0 = a0 + p0;
          float p1 = xrow[c0 + 1] * ek[c0 + 1]; a1 = a1 + p1;
          float p2 = xrow[c0 + 2] * ek[c0 + 2]; a2 = a2 + p2;
          float p3 = xrow[c0 + 3] * ek[c0 + 3]; a3 = a3 + p3;
        }
      const float dot = (a0 + a1) + (a2 + a3);
      const float dist = (se[k] + sx) - 2.0f * dot;
      if (dist < bv || (dist == bv && k < bi)) { bv = dist; bi = k; }
    }
  }
#pragma unroll
  for (int off = 1; off < 32; off <<= 1) {
    const float ov = __shfl_xor(bv, off, 32);
    const int oi = __shfl_xor(bi, off, 32);
    if (ov < bv || (ov == bv && oi < bi)) { bv = ov; bi = oi; }
  }
  if (ln == 0 && cn <= CAP) outids[row] = (float)bi;
}

// ---------- full-row np-exact fallback for overflow rows [verified] ----------
__global__ __launch_bounds__(256) void vq_fallback(const float* __restrict__ x,
                                                   const float* __restrict__ cb,
                                                   const float* __restrict__ se,
                                                   const int* __restrict__ flg,
                                                   const int* __restrict__ nflg,
                                                   float* __restrict__ outids) {
#pragma clang fp contract(off)
  __shared__ float xr[256];
  __shared__ float sxv;
  __shared__ float rv[256];
  __shared__ int ri[256];
  const int t = threadIdx.x;
  const int nf = *nflg;
  for (int fi = blockIdx.x; fi < nf; fi += gridDim.x) {
    const int row = flg[fi];
    const int b = row >> 10, hw = row & 1023;
    __syncthreads();
    xr[t] = x[((size_t)b * CD + t) * HW + hw];
    __syncthreads();
    if (t == 0) {
      float half[2];
      for (int h = 0; h < 2; ++h) {
        float racc[8];
        for (int j = 0; j < 8; ++j) { const float v = xr[h * 128 + j]; racc[j] = v * v; }
        for (int i = 1; i < 16; ++i)
          for (int j = 0; j < 8; ++j) {
            const float v = xr[h * 128 + 8 * i + j];
            const float v2 = v * v;
            racc[j] = racc[j] + v2;
          }
        half[h] = ((racc[0] + racc[1]) + (racc[2] + racc[3])) +
                  ((racc[4] + racc[5]) + (racc[6] + racc[7]));
      }
      sxv = half[0] + half[1];
    }
    __syncthreads();
    float bv = FLT_MAX;
    int bi = 0x7FFFFFFF;
    for (int j = 0; j < 16; ++j) {
      const int k = j * 256 + t;
      const float* ek = cb + (size_t)k * CD;
      float a0 = 0.f, a1 = 0.f, a2 = 0.f, a3 = 0.f;
      for (int B = 0; B < 16; ++B)
        for (int jj = 3; jj >= 0; --jj) {
          const int c0 = 16 * B + 4 * jj;
          float p0 = xr[c0 + 0] * ek[c0 + 0]; a0 = a0 + p0;
          float p1 = xr[c0 + 1] * ek[c0 + 1]; a1 = a1 + p1;
          float p2 = xr[c0 + 2] * ek[c0 + 2]; a2 = a2 + p2;
          float p3 = xr[c0 + 3] * ek[c0 + 3]; a3 = a3 + p3;
        }
      const float dot = (a0 + a1) + (a2 + a3);
      const float dist = (se[k] + sxv) - 2.0f * dot;
      if (dist < bv || (dist == bv && k < bi)) { bv = dist; bi = k; }
    }
    rv[t] = bv; ri[t] = bi;
    __syncthreads();
    for (int off = 128; off > 0; off >>= 1) {
      if (t < off) {
        if (rv[t + off] < rv[t] || (rv[t + off] == rv[t] && ri[t + off] < ri[t])) {
          rv[t] = rv[t + off]; ri[t] = ri[t + off];
        }
      }
      __syncthreads();
    }
    if (t == 0) outids[row] = (float)ri[0];
  }
}

// ---------- emb gather [verified] ----------
__global__ __launch_bounds__(256) void vq_emb_out(const float* __restrict__ outids,
                                                  const float* __restrict__ cb,
                                                  float* __restrict__ out) {
  const int bx = blockIdx.x;
  const int b = bx >> 10;
  const int rem = bx & 1023;
  const int c = rem >> 2;
  const int q = rem & 3;
  const int hw = q * 256 + threadIdx.x;
  const int id = (int)outids[b * HW + hw];
  out[((size_t)(b * CD + c)) * HW + hw] = cb[(size_t)id * CD + c];
}

extern "C" void kernel_launch(void* const* d_in, const int* in_sizes, int n_in,
                              void* d_out, int out_size, void* d_ws, size_t ws_size,
                              hipStream_t stream) {
  const float* x  = (const float*)d_in[0];   // (32,256,32,32) f32
  const float* cb = (const float*)d_in[1];   // (4096,256) f32
  float* out = (float*)d_out;                // [0..32767]=ids, [32768..]=emb

  float* se = (float*)d_ws;                  // 16 KB

  // scratch inside the emb region (8,388,608 floats), overwritten last by gather
  float* sc = out + NRW;
  unsigned short* xh = (unsigned short*)sc;              // 16.8 MB
  unsigned short* eh = (unsigned short*)(sc + 4194304);  // 2.1 MB (pre-swizzled granules)
  int*   cnt  = (int*)(sc + 4751360);                    // 32,768
  int*   flg  = (int*)(sc + 4784128);                    // 32,768
  int*   nflg = (int*)(sc + 4816896);                    // 1
  int*   cand = (int*)(sc + 4816960);                    // 32768*64 ints

  vq_se<<<KC / 32, 256, 0, stream>>>(cb, se);
  vq_cvt_x<<<512, 256, 0, stream>>>(x, xh);
  vq_cvt_e<<<512, 256, 0, stream>>>(cb, eh);
  vq_init<<<128, 256, 0, stream>>>(cnt, nflg);
  vq_gemm<<<512, 256, 0, stream>>>(xh, eh, se, cnt, cand);
  vq_recheck<<<NRW / 8, 256, 0, stream>>>(x, cb, se, cnt, cand, out, flg, nflg);
  vq_fallback<<<512, 256, 0, stream>>>(x, cb, se, flg, nflg, out);
  vq_emb_out<<<32768, 256, 0, stream>>>(out, cb, out + NRW);
}